// Round 8
// baseline (750.884 us; speedup 1.0000x reference)
//
#include <hip/hip_runtime.h>
#include <hip/hip_bf16.h>

#define B_    8
#define C_    64
#define H_    128
#define W_    128
#define K_    9
#define J_    18     // 2*K
#define COUT_ 64
#define TPX   16     // pixels per block
#define CK    576    // C_*K_
#define SROW  584    // sbuf row stride (bf16 elems)
#define XTS   84     // x-tile per-channel stride (u16): 4y*20col + pad; 21 dwords (odd)

typedef __attribute__((ext_vector_type(8))) short short8;
typedef __attribute__((ext_vector_type(4))) float float4v;

// round-to-nearest-even fp32 -> bf16 (scalar fallback)
__device__ __forceinline__ unsigned short f2bf(float f) {
    unsigned int u = __float_as_uint(f);
    u = u + 0x7fffu + ((u >> 16) & 1u);
    return (unsigned short)(u >> 16);
}
// packed pair via v_cvt_pk_bf16_f32 on gfx950 (1 VALU vs 8)
__device__ __forceinline__ unsigned int pk_bf16(float a, float b) {
    union { __hip_bfloat162 h; unsigned int u; } cvt;
    cvt.h = __float22bfloat162_rn(float2{a, b});
    return cvt.u;
}

// conv tap (r*3+s) -> strip index r*7+s. constexpr everywhere (round 3:
// runtime-indexed S[] -> scratch demotion -> GB-scale spill).
constexpr int TMAP[9] = {0, 1, 2, 7, 8, 9, 14, 15, 16};

// -------- pre-kernel: dw f32 -> bf16 (tiny; the NHWC transpose kernel is
// gone — rounds 2-7 showed the pre-pass cost ~60 µs wall vs ~13 µs work) ----
__global__ __launch_bounds__(256)
void conv_dw_bf16(const float* __restrict__ dw, unsigned short* __restrict__ dwb) {
    const int i = blockIdx.x * 256 + threadIdx.x;
    if (i < CK * COUT_) dwb[i] = f2bf(dw[i]);
}

// ---- conv inner loop: guaranteed full unroll + constexpr indices via
// template recursion (pragma-unroll bailed at this size in round 3). Each
// packed weight word read ONCE for all 4 pixels (81 LDS reads/wave).
template<int T>
__device__ __forceinline__ void conv_steps(const unsigned int* __restrict__ owc,
                                           const float (&S)[28], float (&v)[4][J_]) {
    if constexpr (T < 81) {
        const unsigned int pw = owc[T];
        const float wlo = __uint_as_float(pw << 16);
        const float whi = __uint_as_float(pw & 0xffff0000u);
        constexpr int e0 = 2 * T, e1 = 2 * T + 1;
        constexpr int j0 = e0 / 9, p0 = TMAP[e0 % 9];
        constexpr int j1 = e1 / 9, p1 = TMAP[e1 % 9];
        #pragma unroll
        for (int px = 0; px < 4; px++) {
            v[px][j0] = fmaf(wlo, S[p0 + px], v[px][j0]);
            v[px][j1] = fmaf(whi, S[p1 + px], v[px][j1]);
        }
        conv_steps<T + 1>(owc, S, v);
    }
}

// ---- per-pixel softmax + bilinear; I compile-time ----
// No max-subtraction: conv outputs bounded (weights x0.05) -> raw exp safe.
template<int I>
__device__ __forceinline__ void finish_px(float (&v)[J_], const float (&S)[28],
                                          unsigned short* __restrict__ sb) {
    float sum = 0.0f;
    #pragma unroll
    for (int j = 0; j < J_; j++) { v[j] = __expf(v[j]); sum += v[j]; }
    #pragma unroll
    for (int off = 32; off >= 1; off >>= 1) sum += __shfl_xor(sum, off, 64);
    const float inv = 1.0f / sum;
    float smp[K_];
    #pragma unroll
    for (int k = 0; k < K_; k++) {
        const float dy = v[2 * k] * inv;
        const float dx = v[2 * k + 1] * inv;
        const int base = TMAP[k] + I;              // constexpr-folded
        const float a  = S[base],     bb = S[base + 1];
        const float c  = S[base + 7], dd = S[base + 8];
        const float top = a + dx * (bb - a);
        const float bot = c + dx * (dd - c);
        smp[k] = top + dy * (bot - top);
    }
    #pragma unroll
    for (int k = 0; k < 8; k += 2) {
        const unsigned int q = pk_bf16(smp[k], smp[k + 1]);
        sb[k]     = (unsigned short)q;
        sb[k + 1] = (unsigned short)(q >> 16);
    }
    sb[8] = f2bf(smp[8]);
}

// -------- fused kernel (single heavy kernel; NCHW direct) --------
// (256,3): ~168-reg budget vs ~135 live. (256,4)'s 128 budget spills (r5/r6).
template<bool PREB>
__global__ __launch_bounds__(256, 3)
void dcn_fused(const float* __restrict__ x,
               const float* __restrict__ ow,
               const float* __restrict__ ob,
               const float* __restrict__ dw,
               const unsigned short* __restrict__ dwb,
               const float* __restrict__ db,
               float* __restrict__ out) {
    __shared__ unsigned int ow_s[C_ * 81];                       // 20736 B
    __shared__ __align__(16) unsigned short sbuf[TPX * SROW];    // 18688 B
    __shared__ __align__(8)  unsigned short xtile[C_ * XTS];     // 10752 B -> 50176 B total (3 blk/CU)

    const int tid  = threadIdx.x;
    const int wave = tid >> 6;
    const int lane = tid & 63;

    const int bid = blockIdx.x;
    const int b   = bid >> 10;
    const int rem = bid & 1023;
    const int h   = rem >> 3;
    const int w0  = (rem & 7) << 4;

    // stage bf16-packed offset weights
    const float2* ow2 = (const float2*)ow;
    for (int i = tid; i < C_ * 81; i += 256) {
        const float2 f = ow2[i];
        ow_s[i] = pk_bf16(f.x, f.y);
    }

    // ---- stage x-tile: 64c x 4rows x 20cols (w0-1 .. w0+18) as bf16 ----
    // 1280 4-col groups / 256 threads = 5 each; float4 global loads (x is
    // L3-resident; dwordx4 needs only dword alignment on CDNA).
    #pragma unroll
    for (int i = 0; i < 5; i++) {
        const int flat = i * 256 + tid;
        const int row  = flat / 5;               // c*4 + y
        const int seg  = flat - row * 5;         // 0..4
        const int c    = row >> 2;
        const int y    = row & 3;
        const int gy   = h - 1 + y;
        const int gx0  = w0 - 1 + (seg << 2);
        const bool yv  = (unsigned)gy < (unsigned)H_;
        const float* xr = x + ((size_t)(b * C_ + c) * H_ + (gy & 127)) * W_;
        float4 f;
        if (yv && gx0 >= 0 && gx0 + 3 < W_) {
            f = *(const float4*)(xr + gx0);
        } else {
            f.x = (yv && (unsigned)(gx0 + 0) < (unsigned)W_) ? xr[gx0 + 0] : 0.0f;
            f.y = (yv && (unsigned)(gx0 + 1) < (unsigned)W_) ? xr[gx0 + 1] : 0.0f;
            f.z = (yv && (unsigned)(gx0 + 2) < (unsigned)W_) ? xr[gx0 + 2] : 0.0f;
            f.w = (yv && (unsigned)(gx0 + 3) < (unsigned)W_) ? xr[gx0 + 3] : 0.0f;
        }
        uint2 pk;
        pk.x = pk_bf16(f.x, f.y);
        pk.y = pk_bf16(f.z, f.w);
        *(uint2*)(xtile + c * XTS + y * 20 + (seg << 2)) = pk;   // 8B-aligned
    }

    __syncthreads();

    // ---- phase A: conv + softmax + bilinear, all 4 px of this wave ----
    const unsigned int* owc = ow_s + lane * 81;
    const float2* obp = (const float2*)(ob + lane * J_);

    // wave strip = 4 rows x 7 cols from LDS x-tile (local cols wave*4 + 0..6)
    float S[28];
    const unsigned short* xtc = xtile + lane * XTS + (wave << 2);
    #pragma unroll
    for (int r = 0; r < 4; r++) {
        const unsigned int p01 = *(const unsigned int*)(xtc + r * 20);
        const unsigned int p23 = *(const unsigned int*)(xtc + r * 20 + 2);
        const unsigned int p45 = *(const unsigned int*)(xtc + r * 20 + 4);
        const unsigned short s6 = xtc[r * 20 + 6];
        S[r * 7 + 0] = __uint_as_float(p01 << 16);
        S[r * 7 + 1] = __uint_as_float(p01 & 0xffff0000u);
        S[r * 7 + 2] = __uint_as_float(p23 << 16);
        S[r * 7 + 3] = __uint_as_float(p23 & 0xffff0000u);
        S[r * 7 + 4] = __uint_as_float(p45 << 16);
        S[r * 7 + 5] = __uint_as_float(p45 & 0xffff0000u);
        S[r * 7 + 6] = __uint_as_float((unsigned int)s6 << 16);
    }

    float v[4][J_];
    #pragma unroll
    for (int p = 0; p < 9; p++) {
        const float2 f = obp[p];               // bias, L1-hot (4.6 KB)
        #pragma unroll
        for (int px = 0; px < 4; px++) { v[px][2 * p] = f.x; v[px][2 * p + 1] = f.y; }
    }
    conv_steps<0>(owc, S, v);

    unsigned short* sb = sbuf + (wave << 2) * SROW + lane * K_;
    finish_px<0>(v[0], S, sb);
    finish_px<1>(v[1], S, sb + SROW);
    finish_px<2>(v[2], S, sb + 2 * SROW);
    finish_px<3>(v[3], S, sb + 3 * SROW);

    __syncthreads();

    // ---- phase B: MFMA einsum. Per wave: 16 px x 16 outs, K=576 ----
    const int quad = lane >> 4;
    const int o    = (wave << 4) + (lane & 15);
    float4v acc = {0.f, 0.f, 0.f, 0.f};
    const unsigned short* arow = sbuf + (lane & 15) * SROW + quad * 8;  // A[m][k=quad*8+j]
    #pragma unroll
    for (int t = 0; t < 18; t++) {
        short8 afrag = *(const short8*)(arow + t * 32);
        short8 bfrag;
        if (PREB) {
            bfrag = *(const short8*)(dwb + (size_t)o * CK + quad * 8 + t * 32);
        } else {
            const float* brow = dw + (size_t)o * CK + quad * 8 + t * 32;
            const float4 b0 = *(const float4*)brow;
            const float4 b1 = *(const float4*)(brow + 4);
            union { short8 s8; unsigned int u[4]; } bfu;
            bfu.u[0] = pk_bf16(b0.x, b0.y); bfu.u[1] = pk_bf16(b0.z, b0.w);
            bfu.u[2] = pk_bf16(b1.x, b1.y); bfu.u[3] = pk_bf16(b1.z, b1.w);
            bfrag = bfu.s8;
        }
        acc = __builtin_amdgcn_mfma_f32_16x16x32_bf16(afrag, bfrag, acc, 0, 0, 0);
    }
    const float bias = db[o];
    const int px0 = quad << 2;                    // row = quad*4 + reg -> consecutive w
    float4 res;
    res.x = acc[0] + bias; res.y = acc[1] + bias; res.z = acc[2] + bias; res.w = acc[3] + bias;
    *(float4*)(out + ((size_t)(b * COUT_ + o) * H_ + h) * W_ + w0 + px0) = res;
}

extern "C" void kernel_launch(void* const* d_in, const int* in_sizes, int n_in,
                              void* d_out, int out_size, void* d_ws, size_t ws_size,
                              hipStream_t stream) {
    (void)in_sizes; (void)n_in; (void)out_size;
    const float* x  = (const float*)d_in[0];
    const float* ow = (const float*)d_in[1];
    const float* ob = (const float*)d_in[2];
    const float* dw = (const float*)d_in[3];
    const float* db = (const float*)d_in[4];
    float* outp = (float*)d_out;

    const size_t dwbytes = (size_t)CK * COUT_ * sizeof(unsigned short);
    const dim3 grid(B_ * H_ * (W_ / TPX)), blk(256);

    if (ws_size >= dwbytes) {
        unsigned short* dwb = (unsigned short*)d_ws;
        conv_dw_bf16<<<dim3((CK * COUT_ + 255) / 256), blk, 0, stream>>>(dw, dwb);
        dcn_fused<true><<<grid, blk, 0, stream>>>(x, ow, ob, dw, dwb, db, outp);
    } else {
        dcn_fused<false><<<grid, blk, 0, stream>>>(x, ow, ob, dw, nullptr, db, outp);
    }
}